// Round 8
// baseline (642.974 us; speedup 1.0000x reference)
//
#include <hip/hip_runtime.h>
#include <math.h>

typedef unsigned short ushort_t;
typedef __attribute__((ext_vector_type(8))) short bf16x8;
typedef __attribute__((ext_vector_type(4))) float f32x4;
typedef __attribute__((ext_vector_type(8))) unsigned short u16x8;

#define N_TOK 65536
#define DIN 128
#define HD 256
#define DOUT 128
#define NEXP 8
#define MT 64        /* tokens per block; 16 per wave */
#define NSEG 32      /* segments per expert */
#define SEGCAP 2048  /* worst case per segment */
#define SEGTILES (SEGCAP / MT) /* 32 */

#define G_INIT 8192             /* init_out part: N*DOUT/4/256 */
#define G_ROUTER 2048           /* router part: N_TOK/32 */
#define G_PACK 400              /* pack part */

__device__ __forceinline__ unsigned short f2bf(float f) {
    union { float f; unsigned int i; } v; v.f = f;
    unsigned int i = v.i;
    return (unsigned short)((i + 0x7FFFu + ((i >> 16) & 1u)) >> 16); // RNE
}
// LDS A-frag chunk swizzle: breaks the (bank = m*4) alignment of staging /
// epilogue writes (8-way -> <=2-way) while keeping per-quad b128 reads a
// permutation of a contiguous 16-chunk set (conflict-free). Applied on BOTH
// write and read of the same buffer -> any bijection is correct.
__device__ __forceinline__ int swz(int chunk) { return chunk ^ ((chunk >> 4) & 7); }

// ---------------------------------------------------------------------------
// prep kernel: three independent jobs in one dispatch:
// [0,8192) init_out, [8192,10240) router, [10240,10640) pack_weights.
// segcnt is zeroed by a 1KB hipMemsetAsync BEFORE this dispatch.
// ---------------------------------------------------------------------------
#define RT_TPB 32   /* tokens per 256-thread router block */
__global__ __launch_bounds__(256)
void prep_kernel(const float* __restrict__ x,
                 const float* __restrict__ Wg,
                 const float* __restrict__ W1,
                 const float* __restrict__ W2,
                 const float* __restrict__ Wo,
                 const float* __restrict__ bo,
                 int* __restrict__ segcnt,
                 int* __restrict__ list_tok,
                 float* __restrict__ list_w,
                 ushort_t* __restrict__ wt1f,
                 ushort_t* __restrict__ wt2f,
                 ushort_t* __restrict__ wotf,
                 float* __restrict__ out) {
    int tid = threadIdx.x;
    int bx = blockIdx.x;

    if (bx < G_INIT) {
        int gid = bx * 256 + tid;
        float4 b = ((const float4*)bo)[gid & 31];
        ((float4*)out)[gid] = b;
        return;
    }
    if (bx < G_INIT + G_ROUTER) {
        int rb = bx - G_INIT;
        __shared__ float wgsT[NEXP * 132];
        __shared__ int lcnt[NEXP];
        __shared__ int lbase[NEXP];
        if (tid < NEXP) lcnt[tid] = 0;
        for (int i = tid; i < DIN * NEXP; i += 256) {
            int e = i & 7, k = i >> 3;   // Wg[k][e]
            wgsT[e * 132 + k] = Wg[i];
        }
        __syncthreads();

        int s = tid & 7;
        int tl = tid >> 3;
        int n = rb * RT_TPB + tl;

        const float4* xr = (const float4*)(x + (size_t)n * DIN + s * 16);
        float4 xv[4];
#pragma unroll
        for (int j = 0; j < 4; j++) xv[j] = xr[j];

        float lg[NEXP];
#pragma unroll
        for (int e = 0; e < NEXP; e++) {
            const float4* wp = (const float4*)(wgsT + e * 132 + s * 16);
            float a = 0.f;
#pragma unroll
            for (int j = 0; j < 4; j++) {
                float4 wv = wp[j];
                a += xv[j].x * wv.x + xv[j].y * wv.y + xv[j].z * wv.z + xv[j].w * wv.w;
            }
            lg[e] = a;
        }
#pragma unroll
        for (int d = 1; d < 8; d <<= 1) {
#pragma unroll
            for (int e = 0; e < NEXP; e++) lg[e] += __shfl_xor(lg[e], d, 64);
        }
        int e0 = 0; float v0 = lg[0];
#pragma unroll
        for (int e = 1; e < NEXP; e++) if (lg[e] > v0) { v0 = lg[e]; e0 = e; }
        int e1 = -1; float v1 = -3.0e38f;
#pragma unroll
        for (int e = 0; e < NEXP; e++) if (e != e0 && lg[e] > v1) { v1 = lg[e]; e1 = e; }
        float t = expf(v1 - v0);
        float inv = 1.0f / (1.0f + t);
        float w0 = inv, w1 = t * inv;

        bool writer = (s == 0);
        int p0 = 0, p1 = 0;
        if (writer) {
            p0 = atomicAdd(&lcnt[e0], 1);
            p1 = atomicAdd(&lcnt[e1], 1);
        }
        __syncthreads();
        int c = rb & (NSEG - 1);
        if (tid < NEXP) lbase[tid] = atomicAdd(&segcnt[tid * NSEG + c], lcnt[tid]);
        __syncthreads();
        if (writer) {
            int q0 = lbase[e0] + p0;
            int idx0 = (e0 * NSEG + c) * SEGCAP + q0;
            list_tok[idx0] = n;
            list_w[idx0] = w0;
            int q1 = lbase[e1] + p1;
            int idx1 = (e1 * NSEG + c) * SEGCAP + q1;
            list_tok[idx1] = n;
            list_w[idx1] = w1;
        }
        return;
    }
    // ---- pack_weights: fp32 -> bf16 MFMA B-frag order ----
    int id = (bx - G_INIT - G_ROUTER) * 256 + tid;
    const float* src; ushort_t* dst; int Nn, ksteps, c;
    if (id < 32768) {            // W1
        int e = id >> 12; c = id & 4095;
        Nn = HD; ksteps = 4; src = W1 + (size_t)e * DIN * HD; dst = wt1f + (size_t)id * 8;
    } else if (id < 98304) {     // W2
        int t2 = id - 32768; int e = t2 >> 13; c = t2 & 8191;
        Nn = HD; ksteps = 8; src = W2 + (size_t)e * HD * HD; dst = wt2f + (size_t)t2 * 8;
    } else {                     // Wo
        int t2 = id - 98304; c = t2;
        Nn = DOUT; ksteps = 8; src = Wo; dst = wotf + (size_t)t2 * 8;
    }
    int L = c & 63; int kc = c >> 6;
    int kstep = kc % ksteps; int ntile = kc / ksteps;
    int q = L >> 4, m = L & 15;
    int n = ntile * 16 + m; int k0 = kstep * 32 + q * 8;
    u16x8 v;
#pragma unroll
    for (int j = 0; j < 8; j++) v[j] = f2bf(src[(size_t)(k0 + j) * Nn + n]);
    *(u16x8*)dst = v;
}

// ---------------------------------------------------------------------------
// Fused per-expert MLP, BARRIER-FREE: each wave owns 16 tokens end-to-end
// (full N per GEMM), with a wave-private 8KB LDS A-frag buffer (x overlaid,
// then h1, then h2 in place). Intra-wave LDS ops are in-order via lgkmcnt ->
// zero __syncthreads; waves are fully decoupled and latency is hidden by TLP
// (32KB LDS/block -> up to 5 blocks/CU = 20 waves/CU). B-frags are read from
// L2/L1 (4 waves/block + expert-major grid -> same lines, L1 dedup).
// ---------------------------------------------------------------------------
__global__ __launch_bounds__(256, 4)
void expert_kernel(const float* __restrict__ x,
                   const int* __restrict__ segcnt,
                   const int* __restrict__ list_tok,
                   const float* __restrict__ list_w,
                   const ushort_t* __restrict__ wt1f,
                   const ushort_t* __restrict__ wt2f,
                   const ushort_t* __restrict__ wotf,
                   const float* __restrict__ b1,
                   const float* __restrict__ b2,
                   float* __restrict__ out) {
    int bid = blockIdx.x;
    int e = bid >> 10;                 // expert-major: co-resident blocks share weights
    int c = (bid >> 5) & (NSEG - 1);
    int t = bid & (SEGTILES - 1);
    int cnt = segcnt[e * NSEG + c];
    int base = t * MT;
    if (base >= cnt) return;
    int rows = cnt - base; if (rows > MT) rows = MT;
    int lidx = (e * NSEG + c) * SEGCAP + base;

    __shared__ __align__(16) ushort_t bufH[16384]; // 32KB: 4 waves x 8KB private

    int tid = threadIdx.x;
    int lane = tid & 63;
    int w = tid >> 6;
    int q = lane >> 4;
    int mcol = lane & 15;
    int w16 = w * 16;
    if (w16 >= rows) return;           // idle wave: no barriers -> safe to leave
    int nr = rows - w16; if (nr > 16) nr = 16;

    ushort_t* hb = bufH + w * 4096;    // 8KB wave-private
    const bf16x8* Hl = (const bf16x8*)hb;
    const bf16x8* B1 = (const bf16x8*)(wt1f + (size_t)e * 4096 * 8);
    const bf16x8* B2 = (const bf16x8*)(wt2f + (size_t)e * 8192 * 8);
    const bf16x8* B3 = (const bf16x8*)wotf;

    // ---- stage x (16 tokens, fp32 -> bf16) into swizzled A-frag layout ----
    // it-th pass: 4 rows, each row read contiguously by its 16-lane group.
#pragma unroll
    for (int it = 0; it < 4; it++) {
        int m = it * 4 + q;
        int rr = m < nr ? m : nr - 1;
        int tok = list_tok[lidx + w16 + rr];
        const float4* src = (const float4*)(x + (size_t)tok * DIN + mcol * 8);
        float4 lo = src[0], hi = src[1];
        u16x8 v;
        v[0] = f2bf(lo.x); v[1] = f2bf(lo.y); v[2] = f2bf(lo.z); v[3] = f2bf(lo.w);
        v[4] = f2bf(hi.x); v[5] = f2bf(hi.y); v[6] = f2bf(hi.z); v[7] = f2bf(hi.w);
        int chunk = (mcol >> 2) * 64 + (mcol & 3) * 16 + m;
        ((u16x8*)hb)[swz(chunk)] = v;
    }

    // ---- GEMM1: x[16x128] @ W1[128x256] -> h1 (acc 16 n-tiles) ----
    f32x4 acc[16];
#pragma unroll
    for (int nt = 0; nt < 16; nt++) acc[nt] = (f32x4){0.f, 0.f, 0.f, 0.f};
#pragma unroll
    for (int kstep = 0; kstep < 4; kstep++) {
        bf16x8 a = Hl[swz(kstep * 64 + lane)];
#pragma unroll
        for (int nt = 0; nt < 16; nt++) {
            bf16x8 b = B1[(nt * 4 + kstep) * 64 + lane];
            acc[nt] = __builtin_amdgcn_mfma_f32_16x16x32_bf16(a, b, acc[nt], 0, 0, 0);
        }
    }
    // epilogue 1: bias + relu -> h1 in swizzled A-frag layout (in-order WAR ok)
#pragma unroll
    for (int nt = 0; nt < 16; nt++) {
        int nn = nt * 16 + mcol;
        float bias = b1[e * HD + nn];
        int k2 = nn >> 5, qq = (nn >> 3) & 3, jj = nn & 7;
#pragma unroll
        for (int r = 0; r < 4; r++) {
            float v = acc[nt][r] + bias;
            v = v > 0.f ? v : 0.f;
            int chunk = k2 * 64 + qq * 16 + q * 4 + r;
            hb[swz(chunk) * 8 + jj] = f2bf(v);
        }
    }

    // ---- GEMM2: h1[16x256] @ W2[256x256] -> h2 ----
    f32x4 acc2[16];
#pragma unroll
    for (int nt = 0; nt < 16; nt++) acc2[nt] = (f32x4){0.f, 0.f, 0.f, 0.f};
#pragma unroll
    for (int kstep = 0; kstep < 8; kstep++) {
        bf16x8 a = Hl[swz(kstep * 64 + lane)];
#pragma unroll
        for (int nt = 0; nt < 16; nt++) {
            bf16x8 b = B2[(nt * 8 + kstep) * 64 + lane];
            acc2[nt] = __builtin_amdgcn_mfma_f32_16x16x32_bf16(a, b, acc2[nt], 0, 0, 0);
        }
    }
    // epilogue 2: bias + relu -> h2 over h1 (wave-private, in-order)
#pragma unroll
    for (int nt = 0; nt < 16; nt++) {
        int nn = nt * 16 + mcol;
        float bias = b2[e * HD + nn];
        int k2 = nn >> 5, qq = (nn >> 3) & 3, jj = nn & 7;
#pragma unroll
        for (int r = 0; r < 4; r++) {
            float v = acc2[nt][r] + bias;
            v = v > 0.f ? v : 0.f;
            int chunk = k2 * 64 + qq * 16 + q * 4 + r;
            hb[swz(chunk) * 8 + jj] = f2bf(v);
        }
    }

    // ---- GEMM3: h2[16x256] @ Wo[256x128] -> y; weighted atomic combine ----
    f32x4 acc3[8];
#pragma unroll
    for (int nt = 0; nt < 8; nt++) acc3[nt] = (f32x4){0.f, 0.f, 0.f, 0.f};
#pragma unroll
    for (int kstep = 0; kstep < 8; kstep++) {
        bf16x8 a = Hl[swz(kstep * 64 + lane)];
#pragma unroll
        for (int nt = 0; nt < 8; nt++) {
            bf16x8 b = B3[(nt * 8 + kstep) * 64 + lane];
            acc3[nt] = __builtin_amdgcn_mfma_f32_16x16x32_bf16(a, b, acc3[nt], 0, 0, 0);
        }
    }
#pragma unroll
    for (int r = 0; r < 4; r++) {
        int grow = w16 + q * 4 + r;
        if (grow < rows) {
            int tok = list_tok[lidx + grow];
            float wgt = list_w[lidx + grow];
            float* dst = out + (size_t)tok * DOUT;
#pragma unroll
            for (int nt = 0; nt < 8; nt++)
                atomicAdd(&dst[nt * 16 + mcol], wgt * acc3[nt][r]);
        }
    }
}

extern "C" void kernel_launch(void* const* d_in, const int* in_sizes, int n_in,
                              void* d_out, int out_size, void* d_ws, size_t ws_size,
                              hipStream_t stream) {
    const float* x  = (const float*)d_in[0];
    const float* Wg = (const float*)d_in[1];
    const float* W1 = (const float*)d_in[2];
    const float* b1 = (const float*)d_in[3];
    const float* W2 = (const float*)d_in[4];
    const float* b2 = (const float*)d_in[5];
    const float* Wo = (const float*)d_in[6];
    const float* bo = (const float*)d_in[7];
    float* out = (float*)d_out;

    char* ws = (char*)d_ws;
    size_t off = 0;
    int* segcnt    = (int*)(ws + off);    off += 1024; // 8*32 ints
    int* list_tok  = (int*)(ws + off);    off += (size_t)NEXP * NSEG * SEGCAP * 4;
    float* list_w  = (float*)(ws + off);  off += (size_t)NEXP * NSEG * SEGCAP * 4;
    ushort_t* wt1f = (ushort_t*)(ws + off); off += (size_t)NEXP * DIN * HD * 2;
    ushort_t* wt2f = (ushort_t*)(ws + off); off += (size_t)NEXP * HD * HD * 2;
    ushort_t* wotf = (ushort_t*)(ws + off); off += (size_t)HD * DOUT * 2;

    hipMemsetAsync(segcnt, 0, 1024, stream);
    prep_kernel<<<G_INIT + G_ROUTER + G_PACK, 256, 0, stream>>>(
        x, Wg, W1, W2, Wo, bo, segcnt, list_tok, list_w, wt1f, wt2f, wotf, out);
    expert_kernel<<<NEXP * NSEG * SEGTILES, 256, 0, stream>>>(
        x, segcnt, list_tok, list_w, wt1f, wt2f, wotf, b1, b2, out);
}